// Round 8
// baseline (137.605 us; speedup 1.0000x reference)
//
#include <hip/hip_runtime.h>
#include <hip/hip_bf16.h>
#include <math.h>

// NUM_MAPS=512, ZG=512, HID=96, SEQ=8, H1=3, H2=16, NPROC=8. fp32 in/out.
// R7 post-mortem: LDS-prefetch inside kB/kC was neutral (+0.8us) — compiler
// already hoisted weight loads; remaining ~25us controllable = 2 launch gaps
// + per-kernel ramp + serial entry transfers. R8: ONE kernel, 182 blocks
// (all co-resident: 87KB LDS -> 1 blk/CU, 182<=256), two grid barriers via
// ws counters (poison 0xAAAAAAAA is deterministic -> target = poison+182),
// phase-B/C weights DMA'd to LDS during phase A via global_load_lds.

#define WS_ALPHA 0
#define WS_Q     512
#define WS_QKV   608      // 8*2304 -> 19040
#define WS_K2    19040    // 8*768  -> 25184
#define WS_V2    25184    // 8*768  -> 31328
#define WS_QQ    31328    // 8*96   -> 32096
#define WS_BAR   49152    // two uints (ws elements 49152, 49153)

#define GRID    182
#define BAR_TGT (0xAAAAAAAAu + 182u)
#define PF      6272      // prefetch region offset (floats) in dynamic LDS

static __device__ __forceinline__ void gl_lds16(const float4* g, float4* l) {
    __builtin_amdgcn_global_load_lds(
        (const __attribute__((address_space(1))) void*)g,
        (__attribute__((address_space(3))) void*)l, 16, 0, 0);
}

static __device__ __forceinline__ void grid_bar(unsigned* c, int tid) {
    __syncthreads();                 // drains vmcnt/lgkmcnt for this block
    if (tid == 0) {
        __threadfence();             // release (device scope)
        __hip_atomic_fetch_add(c, 1u, __ATOMIC_ACQ_REL, __HIP_MEMORY_SCOPE_AGENT);
        while (__hip_atomic_load(c, __ATOMIC_ACQUIRE, __HIP_MEMORY_SCOPE_AGENT)
               != BAR_TGT)
            __builtin_amdgcn_s_sleep(2);
        __threadfence();             // acquire
    }
    __syncthreads();
}

// ---------------------------------------------------------------------------
// Fused kernel, 182 blocks x 256, ~87KB dynamic LDS.
// Phase A: QKV1 (blk 0..143), alpha (144..175), q (176..181)    [= R7 kA]
//   + async LDS prefetch of phase-B/C weights per block role.
// barrier -> Phase B: attn1+fc1+K2/V2 (blk 0..47), Qq (48..71)  [= R7 kB]
// barrier -> Phase C: attn2+fc2+Wo+epilogue (blk 72..135)       [= R7 kC]
// ---------------------------------------------------------------------------
__global__ __launch_bounds__(256) void k_fused(
    const float* __restrict__ gate, const float* __restrict__ x,
    const float* __restrict__ Wa,   const float* __restrict__ ba,
    const float* __restrict__ Wqr,  const float* __restrict__ bqr,
    const float* __restrict__ P,    const float* __restrict__ De,
    const float* __restrict__ regs, const float* __restrict__ Wq1,
    const float* __restrict__ Wk1,  const float* __restrict__ Wv1,
    const float* __restrict__ fc1w, const float* __restrict__ Wq2,
    const float* __restrict__ Wk2,  const float* __restrict__ Wv2,
    const float* __restrict__ fc2w, const float* __restrict__ Wo,
    float* __restrict__ ws, float* __restrict__ out)
{
    extern __shared__ float sm[];
    const int b = blockIdx.x, tid = threadIdx.x;
    unsigned* bar = (unsigned*)(ws + WS_BAR);
    const float rs = 0.10206207261596577f;   // 1/sqrt(96)

    // ---------------- entry: async weight prefetch (DMA to LDS) ----------
    if (b < 48) {                 // phase-B heavy role: fc1 + Wk2/Wv2 slice
        const int proc = b / 6, rem = b % 6, mat = rem / 3, t = rem % 3;
        const float4* F4 = (const float4*)fc1w + proc * 2304;
        float4* D4 = (float4*)(sm + PF);
        #pragma unroll
        for (int r = 0; r < 9; ++r)
            gl_lds16(F4 + tid + 256 * r, D4 + tid + 256 * r);
        const float4* KV4 = (const float4*)(mat ? Wv2 : Wk2) + proc * 2304;
        float4* E4 = (float4*)(sm + PF + 9216);
        #pragma unroll
        for (int r = 0; r < 3; ++r) {
            const int idx = tid + 256 * r, row = idx >> 3, q4 = idx & 7;
            gl_lds16(KV4 + row * 24 + t * 8 + q4, E4 + idx);
        }
    } else if (b < 72) {          // phase-B Qq role: Wq2 slice
        const int b2 = b - 48, proc = b2 / 3, t = b2 % 3;
        const float4* Q4 = (const float4*)Wq2 + proc * 2304;
        float4* E4 = (float4*)(sm + PF);
        #pragma unroll
        for (int r = 0; r < 3; ++r) {
            const int idx = tid + 256 * r, row = idx >> 3, q4 = idx & 7;
            gl_lds16(Q4 + row * 24 + t * 8 + q4, E4 + idx);
        }
    } else if (b < 136) {         // phase-C role: fc2 + Wo slice + De + regs
        const int cb = b - 72, proc = cb >> 3, e = cb & 7;
        const float4* F4 = (const float4*)fc2w + proc * 2304;
        float4* D4 = (float4*)(sm + PF);
        #pragma unroll
        for (int r = 0; r < 9; ++r)
            gl_lds16(F4 + tid + 256 * r, D4 + tid + 256 * r);
        const float4* W4 = (const float4*)Wo + proc * 12288;
        float4* E4 = (float4*)(sm + PF + 9216);
        #pragma unroll
        for (int r = 0; r < 6; ++r) {
            const int idx = tid + 256 * r, row = idx >> 4, q4 = idx & 15;
            gl_lds16(W4 + row * 128 + e * 16 + q4, E4 + idx);
        }
        const float4* De4 = (const float4*)De + proc * 1024 + e * 128;
        float4* G4 = (float4*)(sm + PF + 15360);
        if (tid < 128) gl_lds16(De4 + tid, G4 + tid);
        const float4* R4 = (const float4*)regs + proc * 128 + e * 16;
        float4* H4 = (float4*)(sm + PF + 15872);
        if (tid < 16) gl_lds16(R4 + tid, H4 + tid);
    }

    // ---------------- phase A ----------------
    if (b < 144) {
        const int proc = b / 18, rem = b % 18, mat = rem / 6, six = rem % 6;
        const int hl = tid & 15, ks = tid >> 4;        // ks 0..15
        const int h = six * 16 + hl;
        const float* W = (mat == 0 ? Wq1 : (mat == 1 ? Wk1 : Wv1))
                         + proc * 49152 + (ks * 32) * 96 + h;
        float wreg[32];
        #pragma unroll
        for (int m2 = 0; m2 < 32; ++m2) wreg[m2] = W[m2 * 96];
        float* sK = sm;            // skewed K tile, 4224 floats
        float* sp = sm + 4224;     // partials, 2048 floats
        const float4* P4 = (const float4*)(P + proc * 4096);
        for (int i = tid; i < 1024; i += 256) {
            float4 v = P4[i];
            const int c = i >> 1, off = (i & 1) * 4;
            const int cp = c + (c >> 5);
            sK[(off + 0) * 528 + cp] = v.x;
            sK[(off + 1) * 528 + cp] = v.y;
            sK[(off + 2) * 528 + cp] = v.z;
            sK[(off + 3) * 528 + cp] = v.w;
        }
        __syncthreads();
        const float* Kb = sK + ks * 33;
        float acc[8] = {0.f,0.f,0.f,0.f,0.f,0.f,0.f,0.f};
        #pragma unroll
        for (int m2 = 0; m2 < 32; ++m2) {
            const float w = wreg[m2];
            const float* Kc = Kb + m2;
            #pragma unroll
            for (int s = 0; s < 8; ++s) acc[s] += Kc[s * 528] * w;
        }
        float* spb = sp + ks * 128 + hl * 8;
        #pragma unroll
        for (int s = 0; s < 8; ++s) spb[s] = acc[s];
        __syncthreads();
        if (tid < 128) {           // tid = hl2*8 + s
            float a = 0.f;
            #pragma unroll
            for (int u = 0; u < 16; ++u) a += sp[u * 128 + tid];
            const int hl2 = tid >> 3, s = tid & 7;
            ws[WS_QKV + proc * 2304 + mat * 768 + s * 96 + six * 16 + hl2] = a;
        }
    } else if (b < 176) {
        const int ml = tid & 15, ks = tid >> 4;
        const int m = (b - 144) * 16 + ml;
        const float* W = Wa + (ks * 32) * 512 + m;
        float wreg[32];
        #pragma unroll
        for (int k = 0; k < 32; ++k) wreg[k] = W[k * 512];
        float* sK = sm; float* sp = sm + 4224;
        for (int k = tid; k < 512; k += 256) sK[k] = x[k];
        __syncthreads();
        const float* xq = sK + ks * 32;
        float acc = 0.f;
        #pragma unroll
        for (int k = 0; k < 32; ++k) acc += xq[k] * wreg[k];
        sp[tid] = acc;
        __syncthreads();
        if (tid < 16) {
            float a = ba[(b - 144) * 16 + tid];
            #pragma unroll
            for (int u = 0; u < 16; ++u) a += sp[u * 16 + tid];
            ws[WS_ALPHA + (b - 144) * 16 + tid] = 1.f / (1.f + __expf(-a));
        }
    } else {
        const int hl = tid & 15, ks = tid >> 4;
        const int h = (b - 176) * 16 + hl;             // 6*16 = 96
        const float* W = Wqr + (ks * 32) * 96 + h;
        float wreg[32];
        #pragma unroll
        for (int k = 0; k < 32; ++k) wreg[k] = W[k * 96];
        float* sK = sm; float* sp = sm + 4224;
        for (int k = tid; k < 512; k += 256) sK[k] = x[k];
        __syncthreads();
        const float* xq = sK + ks * 32;
        float acc = 0.f;
        #pragma unroll
        for (int k = 0; k < 32; ++k) acc += xq[k] * wreg[k];
        sp[tid] = acc;
        __syncthreads();
        if (tid < 16) {
            float a = bqr[(b - 176) * 16 + tid];
            #pragma unroll
            for (int u = 0; u < 16; ++u) a += sp[u * 16 + tid];
            ws[WS_Q + (b - 176) * 16 + tid] = fmaxf(a, 0.f);
        }
    }

    grid_bar(bar + 0, tid);    // QKV1/alpha/q visible; prefetch DMA drained

    // ---------------- phase B ----------------
    if (b < 48) {
        const int proc = b / 6, rem = b % 6, mat = rem / 3, t = rem % 3;
        float* sQk = sm;        float* sKk = sm + 768;  float* sVv = sm + 1536;
        float* sH  = sm + 2304; float* sH2 = sm + 3072; float* sS  = sm + 3840;
        const float* sWf1 = sm + PF;           // fc1 [i][j]
        const float* sWkv = sm + PF + 9216;    // Wk2/Wv2 slice [i][jl]
        const float* qkv = ws + WS_QKV + proc * 2304;
        for (int i = tid; i < 768; i += 256) {
            sQk[i] = qkv[i]; sKk[i] = qkv[768 + i]; sVv[i] = qkv[1536 + i];
        }
        __syncthreads();
        if (tid < 192) {        // attn1 logits (h0, si, sk)
            const int h0 = tid / 64, r64 = tid % 64, si = r64 / 8, sk = r64 % 8;
            float acc = 0.f;
            #pragma unroll
            for (int d = 0; d < 32; ++d)
                acc += sQk[si * 96 + h0 * 32 + d] * sKk[sk * 96 + h0 * 32 + d];
            sS[tid] = acc * rs;
        }
        __syncthreads();
        if (tid < 24) {         // softmax row -> probs in place
            float* row = sS + tid * 8;
            float mx = row[0];
            #pragma unroll
            for (int k = 1; k < 8; ++k) mx = fmaxf(mx, row[k]);
            float e[8], sum = 0.f;
            #pragma unroll
            for (int k = 0; k < 8; ++k) { e[k] = __expf(row[k] - mx); sum += e[k]; }
            const float inv = 1.f / sum;
            #pragma unroll
            for (int k = 0; k < 8; ++k) row[k] = e[k] * inv;
        }
        __syncthreads();
        if (tid < 192) {        // AV + residual (h0, si, dq): 4 d's each
            const int h0 = tid / 64, r64 = tid % 64, si = r64 / 8, dq = r64 % 8;
            const float* e = sS + h0 * 64 + si * 8;
            float o0 = 0.f, o1 = 0.f, o2 = 0.f, o3 = 0.f;
            #pragma unroll
            for (int k = 0; k < 8; ++k) {
                const float ek = e[k];
                const float* v = sVv + k * 96 + h0 * 32 + dq * 4;
                o0 += ek*v[0]; o1 += ek*v[1]; o2 += ek*v[2]; o3 += ek*v[3];
            }
            const int base = si * 96 + h0 * 32 + dq * 4;
            sH[base+0] = sQk[base+0] + o0;  sH[base+1] = sQk[base+1] + o1;
            sH[base+2] = sQk[base+2] + o2;  sH[base+3] = sQk[base+3] + o3;
        }
        __syncthreads();
        #pragma unroll
        for (int r = 0; r < 3; ++r) {   // fc1 (full, redundant)
            const int idx = tid + 256 * r, s = idx / 96, j = idx % 96;
            const float* Hs = sH + s * 96;
            float acc = 0.f;
            #pragma unroll
            for (int i = 0; i < 96; ++i) acc += Hs[i] * sWf1[i * 96 + j];
            sH2[idx] = sH[idx] + fmaxf(acc, 0.f);
        }
        __syncthreads();
        const int s = tid >> 5, jl = tid & 31, j = t * 32 + jl;
        const float* Hs = sH2 + s * 96;
        float acc = 0.f;
        #pragma unroll
        for (int i = 0; i < 96; ++i) acc += Hs[i] * sWkv[i * 32 + jl];
        ws[(mat ? WS_V2 : WS_K2) + proc * 768 + s * 96 + j] = acc;
    } else if (b < 72) {
        const int b2 = b - 48, proc = b2 / 3, t = b2 % 3;
        float* sq = sm; float* sp2 = sm + 128;
        const float* sWq2 = sm + PF;
        if (tid < 96) sq[tid] = ws[WS_Q + tid];
        __syncthreads();
        const int jl = tid & 31, ks = tid >> 5, j = 32 * t + jl;
        float acc = 0.f;
        #pragma unroll
        for (int i = 0; i < 12; ++i)
            acc += sq[12 * ks + i] * sWq2[(12 * ks + i) * 32 + jl];
        sp2[tid] = acc;
        __syncthreads();
        if (ks == 0) {
            float a = 0.f;
            #pragma unroll
            for (int u = 0; u < 8; ++u) a += sp2[jl + 32 * u];
            ws[WS_QQ + proc * 96 + j] = a;
        }
    }

    grid_bar(bar + 1, tid);    // K2/V2/Qq visible

    // ---------------- phase C ----------------
    if (b >= 72 && b < 136) {
        const int cb = b - 72, proc = cb >> 3, e = cb & 7;
        float* sK2 = sm;         float* sV2 = sm + 768;
        float* sQq = sm + 1536;  float* sO  = sm + 1632;
        float* sOf = sm + 1728;  float* sE2 = sm + 1824;
        float* sg  = sm + 1952;  float* spc = sm + 1984;
        const float* sWf2 = sm + PF;            // fc2 [i][j]
        const float* sWo  = sm + PF + 9216;     // Wo slice [h][ml]
        const float* sDe  = sm + PF + 15360;    // De slice (512)
        const float* sRg  = sm + PF + 15872;    // regs slice (64)
        for (int i = tid; i < 768; i += 256) {
            sK2[i] = ws[WS_K2 + proc * 768 + i];
            sV2[i] = ws[WS_V2 + proc * 768 + i];
        }
        if (tid < 96) sQq[tid] = ws[WS_QQ + proc * 96 + tid];
        else if (tid < 104) sg[tid - 96] = gate[tid - 96];
        __syncthreads();
        if (tid < 16) {         // attn2 probs: 16 heads, d=6
            const int h0 = tid;
            float lg[8], mx = -1e30f;
            #pragma unroll
            for (int k = 0; k < 8; ++k) {
                float acc = 0.f;
                #pragma unroll
                for (int d = 0; d < 6; ++d)
                    acc += sQq[h0 * 6 + d] * sK2[k * 96 + h0 * 6 + d];
                lg[k] = acc * rs; mx = fmaxf(mx, lg[k]);
            }
            float ex[8], sum = 0.f;
            #pragma unroll
            for (int k = 0; k < 8; ++k) { ex[k] = __expf(lg[k] - mx); sum += ex[k]; }
            const float inv = 1.f / sum;
            #pragma unroll
            for (int k = 0; k < 8; ++k) sE2[h0 * 8 + k] = ex[k] * inv;
        }
        __syncthreads();
        if (tid < 96) {         // AV + residual
            const int h0 = tid / 6;
            float o = 0.f;
            #pragma unroll
            for (int k = 0; k < 8; ++k) o += sE2[h0 * 8 + k] * sV2[k * 96 + tid];
            sO[tid] = sQq[tid] + o;
        }
        __syncthreads();
        if (tid < 192) {        // fc2 from LDS, 2-way k-split
            const int j = tid % 96, k2 = tid / 96;
            const float* Os = sO + k2 * 48;
            float acc = 0.f;
            #pragma unroll
            for (int i = 0; i < 48; ++i)
                acc += Os[i] * sWf2[(k2 * 48 + i) * 96 + j];
            spc[tid] = acc;
        }
        __syncthreads();
        if (tid < 96) sOf[tid] = sO[tid] + fmaxf(spc[tid] + spc[96 + tid], 0.f);
        __syncthreads();
        const int ml = tid & 63, ks = tid >> 6, m = 64 * e + ml;
        float acc = 0.f;
        #pragma unroll
        for (int i = 0; i < 24; ++i)
            acc += sOf[24 * ks + i] * sWo[(24 * ks + i) * 64 + ml];
        spc[tid] = acc;
        __syncthreads();
        if (ks == 0) {
            const float tr = spc[ml] + spc[ml + 64] + spc[ml + 128] + spc[ml + 192];
            float de = 0.f;
            #pragma unroll
            for (int s = 0; s < 8; ++s) de += sDe[ml * 8 + s] * sg[s];
            const float av = ws[WS_ALPHA + m];
            const float mix = av * tr + (1.f - av) * de;
            const int pt = proc & 3;             // gamma gets +1, beta not
            const float off = (pt == 0 || pt == 2) ? 1.f : 0.f;
            out[proc * 512 + m] = mix * sRg[ml] + off;
        }
    }
}

extern "C" void kernel_launch(void* const* d_in, const int* in_sizes, int n_in,
                              void* d_out, int out_size, void* d_ws, size_t ws_size,
                              hipStream_t stream)
{
    const float* gate = (const float*)d_in[0];
    const float* x    = (const float*)d_in[1];
    const float* Wa   = (const float*)d_in[2];
    const float* ba   = (const float*)d_in[3];
    const float* Wqr  = (const float*)d_in[4];
    const float* bqr  = (const float*)d_in[5];
    const float* P    = (const float*)d_in[6];
    const float* De   = (const float*)d_in[7];
    const float* regs = (const float*)d_in[8];
    const float* Wq1  = (const float*)d_in[9];
    const float* Wk1  = (const float*)d_in[10];
    const float* Wv1  = (const float*)d_in[11];
    const float* fc1  = (const float*)d_in[12];
    const float* Wq2  = (const float*)d_in[13];
    const float* Wk2  = (const float*)d_in[14];
    const float* Wv2  = (const float*)d_in[15];
    const float* fc2  = (const float*)d_in[16];
    const float* Wo   = (const float*)d_in[17];
    float* ws = (float*)d_ws;

    const size_t lds_bytes = (PF + 15936) * sizeof(float);   // 88832 B
    hipLaunchKernelGGL(k_fused, dim3(GRID), dim3(256), lds_bytes, stream,
                       gate, x, Wa, ba, Wqr, bqr, P, De, regs,
                       Wq1, Wk1, Wv1, fc1, Wq2, Wk2, Wv2, fc2, Wo,
                       ws, (float*)d_out);
}

// Round 9
// 109.383 us; speedup vs baseline: 1.2580x; 1.2580x over previous
//
#include <hip/hip_runtime.h>
#include <hip/hip_bf16.h>
#include <math.h>

// NUM_MAPS=512, ZG=512, HID=96, SEQ=8, H1=3, H2=16, NPROC=8. fp32 in/out.
// R8 post-mortem: fused single-kernel with poison-seeded spin grid-barrier
// REGRESSED (25us chain -> 55us fused). Agent-scope acquire polls invalidate
// per-XCD caches every iteration (FETCH 10.3MB refetch, conflict count 34x),
// stragglers compound; __syncthreads drains the DMA prefetch queue (m97
// vmcnt(0) drain). Kernel-boundary sync at ~2.5us/gap IS the cheap grid
// barrier on this chip. R9: exact revert to R7 (verified 108.97us):
// kA (182) -> kB (72) -> kC (64), LDS burst-staged weights.

#define WS_ALPHA 0
#define WS_Q     512
#define WS_QKV   608      // 8*2304 -> 19040
#define WS_K2    19040    // 8*768  -> 25184
#define WS_V2    25184    // 8*768  -> 31328
#define WS_QQ    31328    // 8*96   -> 32096

// ---------------------------------------------------------------------------
// KA (182 x 256):
//  blk 0..143   : QKV1. (proc, mat, sixth): 16 h x 8 s outs; thread (hl16,
//                 ks16): 32 W loads hoisted to regs, K tile skewed in LDS.
//  blk 144..175 : alpha. 16 m/blk, 16-way k-split, W hoisted.
//  blk 176..181 : q. 16 h/blk, 16-way k-split, W hoisted.
// ---------------------------------------------------------------------------
__global__ __launch_bounds__(256) void kA_qkv_alpha_q(
    const float* __restrict__ x, const float* __restrict__ Wa,
    const float* __restrict__ ba, const float* __restrict__ Wqr,
    const float* __restrict__ bqr, const float* __restrict__ P,
    const float* __restrict__ Wq1, const float* __restrict__ Wk1,
    const float* __restrict__ Wv1, float* __restrict__ ws)
{
    __shared__ float sK[8 * 528];   // skewed K tile (c -> c + c/32), or x
    __shared__ float sp[2048];      // partial sums
    const int blk = blockIdx.x, tid = threadIdx.x;

    if (blk < 144) {
        const int proc = blk / 18, rem = blk % 18, mat = rem / 6, six = rem % 6;
        const int hl = tid & 15, ks = tid >> 4;        // ks 0..15
        const int h = six * 16 + hl;
        const float* W = (mat == 0 ? Wq1 : (mat == 1 ? Wk1 : Wv1))
                         + proc * 49152 + (ks * 32) * 96 + h;
        float wreg[32];
        #pragma unroll
        for (int m2 = 0; m2 < 32; ++m2) wreg[m2] = W[m2 * 96];  // issued early
        // stage K[s][c] = P[proc,c,s], column skewed c -> c + (c>>5)
        const float4* P4 = (const float4*)(P + proc * 4096);
        for (int i = tid; i < 1024; i += 256) {
            float4 v = P4[i];
            const int c = i >> 1, off = (i & 1) * 4;
            const int cp = c + (c >> 5);
            sK[(off + 0) * 528 + cp] = v.x;
            sK[(off + 1) * 528 + cp] = v.y;
            sK[(off + 2) * 528 + cp] = v.z;
            sK[(off + 3) * 528 + cp] = v.w;
        }
        __syncthreads();
        const float* Kb = sK + ks * 33;                // skewed base
        float acc[8] = {0.f,0.f,0.f,0.f,0.f,0.f,0.f,0.f};
        #pragma unroll
        for (int m2 = 0; m2 < 32; ++m2) {
            const float w = wreg[m2];
            const float* Kc = Kb + m2;
            #pragma unroll
            for (int s = 0; s < 8; ++s) acc[s] += Kc[s * 528] * w;
        }
        float* spb = sp + ks * 128 + hl * 8;
        #pragma unroll
        for (int s = 0; s < 8; ++s) spb[s] = acc[s];
        __syncthreads();
        if (tid < 128) {            // tid = hl2*8 + s
            float a = 0.f;
            #pragma unroll
            for (int u = 0; u < 16; ++u) a += sp[u * 128 + tid];
            const int hl2 = tid >> 3, s = tid & 7;
            ws[WS_QKV + proc * 2304 + mat * 768 + s * 96 + six * 16 + hl2] = a;
        }
    } else if (blk < 176) {
        const int ml = tid & 15, ks = tid >> 4;        // 32 k each
        const int m = (blk - 144) * 16 + ml;
        const float* W = Wa + (ks * 32) * 512 + m;
        float wreg[32];
        #pragma unroll
        for (int k = 0; k < 32; ++k) wreg[k] = W[k * 512];
        for (int k = tid; k < 512; k += 256) sK[k] = x[k];
        __syncthreads();
        const float* xq = sK + ks * 32;
        float acc = 0.f;
        #pragma unroll
        for (int k = 0; k < 32; ++k) acc += xq[k] * wreg[k];
        sp[tid] = acc;
        __syncthreads();
        if (tid < 16) {
            float a = ba[(blk - 144) * 16 + tid];
            #pragma unroll
            for (int u = 0; u < 16; ++u) a += sp[u * 16 + tid];
            ws[WS_ALPHA + (blk - 144) * 16 + tid] = 1.f / (1.f + __expf(-a));
        }
    } else {
        const int hl = tid & 15, ks = tid >> 4;        // 32 k each
        const int h = (blk - 176) * 16 + hl;           // 6*16 = 96
        const float* W = Wqr + (ks * 32) * 96 + h;
        float wreg[32];
        #pragma unroll
        for (int k = 0; k < 32; ++k) wreg[k] = W[k * 96];
        for (int k = tid; k < 512; k += 256) sK[k] = x[k];
        __syncthreads();
        const float* xq = sK + ks * 32;
        float acc = 0.f;
        #pragma unroll
        for (int k = 0; k < 32; ++k) acc += xq[k] * wreg[k];
        sp[tid] = acc;
        __syncthreads();
        if (tid < 16) {
            float a = bqr[(blk - 176) * 16 + tid];
            #pragma unroll
            for (int u = 0; u < 16; ++u) a += sp[u * 16 + tid];
            ws[WS_Q + (blk - 176) * 16 + tid] = fmaxf(a, 0.f);
        }
    }
}

// ---------------------------------------------------------------------------
// KB (72 x 256): blk<48: (proc, mat, third) — entry burst-stages fc1 (36KB)
// + Wk2/Wv2 slice (12KB) into LDS, then attn1 -> fc1 -> K2/V2 slice.
// blk 48..71: Qq = q @ Wq2 (proc, third), 8-way k-split.
// ---------------------------------------------------------------------------
__global__ __launch_bounds__(256) void kB_attn1_fc1_kv2(
    const float* __restrict__ fc1w, const float* __restrict__ Wk2,
    const float* __restrict__ Wv2, const float* __restrict__ Wq2,
    float* __restrict__ ws)
{
    const int b = blockIdx.x, tid = threadIdx.x;
    const float rs = 0.10206207261596577f;  // 1/sqrt(96)

    if (b < 48) {
        const int proc = b / 6, rem = b % 6, mat = rem / 3, t = rem % 3;
        __shared__ float sQk[768], sKk[768], sVv[768], sH[768], sH2[768], sS[192];
        __shared__ float sWf1[9216];     // fc1, row-major [i][j]
        __shared__ float sWkv[96 * 32];  // Wk2/Wv2 column slice [i][jl]

        // ---- entry burst: all weight bytes, coalesced float4, once ----
        {
            const float4* F4 = (const float4*)fc1w + proc * 2304;
            float4* D4 = (float4*)sWf1;
            #pragma unroll
            for (int r = 0; r < 9; ++r) D4[tid + 256 * r] = F4[tid + 256 * r];
            const float4* KV4 = (const float4*)(mat ? Wv2 : Wk2);
            float4* E4 = (float4*)sWkv;
            #pragma unroll
            for (int r = 0; r < 3; ++r) {
                const int idx = tid + 256 * r;          // 768 float4
                const int row = idx >> 3, q4 = idx & 7;
                E4[row * 8 + q4] = KV4[proc * 2304 + row * 24 + t * 8 + q4];
            }
        }
        const float* qkv = ws + WS_QKV + proc * 2304;
        for (int i = tid; i < 768; i += 256) {
            sQk[i] = qkv[i]; sKk[i] = qkv[768 + i]; sVv[i] = qkv[1536 + i];
        }
        __syncthreads();

        if (tid < 192) {       // attn1 logits (h0, si, sk)
            const int h0 = tid / 64, r64 = tid % 64, si = r64 / 8, sk = r64 % 8;
            float acc = 0.f;
            #pragma unroll
            for (int d = 0; d < 32; ++d)
                acc += sQk[si * 96 + h0 * 32 + d] * sKk[sk * 96 + h0 * 32 + d];
            sS[tid] = acc * rs;
        }
        __syncthreads();
        if (tid < 24) {        // softmax row -> probs in place
            float* row = sS + tid * 8;
            float mx = row[0];
            #pragma unroll
            for (int k = 1; k < 8; ++k) mx = fmaxf(mx, row[k]);
            float e[8], sum = 0.f;
            #pragma unroll
            for (int k = 0; k < 8; ++k) { e[k] = __expf(row[k] - mx); sum += e[k]; }
            const float inv = 1.f / sum;
            #pragma unroll
            for (int k = 0; k < 8; ++k) row[k] = e[k] * inv;
        }
        __syncthreads();
        if (tid < 192) {       // AV + residual (h0, si, dq): 4 d's each
            const int h0 = tid / 64, r64 = tid % 64, si = r64 / 8, dq = r64 % 8;
            const float* e = sS + h0 * 64 + si * 8;
            float o0 = 0.f, o1 = 0.f, o2 = 0.f, o3 = 0.f;
            #pragma unroll
            for (int k = 0; k < 8; ++k) {
                const float ek = e[k];
                const float* v = sVv + k * 96 + h0 * 32 + dq * 4;
                o0 += ek*v[0]; o1 += ek*v[1]; o2 += ek*v[2]; o3 += ek*v[3];
            }
            const int base = si * 96 + h0 * 32 + dq * 4;
            sH[base+0] = sQk[base+0] + o0;  sH[base+1] = sQk[base+1] + o1;
            sH[base+2] = sQk[base+2] + o2;  sH[base+3] = sQk[base+3] + o3;
        }
        __syncthreads();
        // fc1 from LDS (full, redundant): 3 outputs/thread
        #pragma unroll
        for (int r = 0; r < 3; ++r) {
            const int idx = tid + 256 * r, s = idx / 96, j = idx % 96;
            const float* Hs = sH + s * 96;
            float acc = 0.f;
            #pragma unroll
            for (int i = 0; i < 96; ++i) acc += Hs[i] * sWf1[i * 96 + j];
            sH2[idx] = sH[idx] + fmaxf(acc, 0.f);
        }
        __syncthreads();
        // K2/V2 slice from LDS: (s, jl)
        const int s = tid >> 5, jl = tid & 31, j = t * 32 + jl;
        const float* Hs = sH2 + s * 96;
        float acc = 0.f;
        #pragma unroll
        for (int i = 0; i < 96; ++i) acc += Hs[i] * sWkv[i * 32 + jl];
        ws[(mat ? WS_V2 : WS_K2) + proc * 768 + s * 96 + j] = acc;
    } else {
        const int b2 = b - 48, proc = b2 / 3, t = b2 % 3;
        __shared__ float sq[96], sp[256];
        if (tid < 96) sq[tid] = ws[WS_Q + tid];
        __syncthreads();
        const int jl = tid & 31, ks = tid >> 5;
        const int j = 32 * t + jl;
        const float* W = Wq2 + proc * 9216 + j;
        float acc = 0.f;
        #pragma unroll
        for (int i = 0; i < 12; ++i)
            acc += sq[12 * ks + i] * W[(12 * ks + i) * 96];
        sp[tid] = acc;
        __syncthreads();
        if (ks == 0) {
            float a = 0.f;
            #pragma unroll
            for (int u = 0; u < 8; ++u) a += sp[jl + 32 * u];
            ws[WS_QQ + proc * 96 + j] = a;
        }
    }
}

// ---------------------------------------------------------------------------
// KC (64 x 256): (proc, eighth). Entry burst-stages fc2 (36KB) + Wo slice
// (24KB) into LDS + K2/V2/Qq from ws + De/alpha/regs into regs. Then attn2,
// fc2 (LDS), Wo slice (LDS) + epilogue.
// ---------------------------------------------------------------------------
__global__ __launch_bounds__(256) void kC_attn2_fc2_out(
    const float* __restrict__ gate, const float* __restrict__ De,
    const float* __restrict__ regs, const float* __restrict__ fc2w,
    const float* __restrict__ Wo, const float* __restrict__ ws,
    float* __restrict__ out)
{
    const int b = blockIdx.x, proc = b >> 3, e = b & 7, tid = threadIdx.x;
    __shared__ float sK2[768], sV2[768];
    __shared__ float sQq[96], sO[96], sOf[96], sE2[128], sg[8], sp[256];
    __shared__ float sWf2[9216];     // fc2 [i][j]
    __shared__ float sWo[96 * 64];   // Wo slice [h][ml]
    const float rs = 0.10206207261596577f;

    // ---- entry burst ----
    {
        const float4* F4 = (const float4*)fc2w + proc * 2304;
        float4* D4 = (float4*)sWf2;
        #pragma unroll
        for (int r = 0; r < 9; ++r) D4[tid + 256 * r] = F4[tid + 256 * r];
        const float4* W4 = (const float4*)Wo;
        float4* E4 = (float4*)sWo;
        #pragma unroll
        for (int r = 0; r < 6; ++r) {
            const int idx = tid + 256 * r;              // 1536 float4
            const int row = idx >> 4, q4 = idx & 15;
            E4[row * 16 + q4] = W4[proc * 12288 + row * 128 + e * 16 + q4];
        }
    }
    const int ml = tid & 63, ks = tid >> 6;
    const int m = 64 * e + ml;
    // epilogue operands prefetched into regs (redundant across ks, cheap)
    const float4* Dp4 = (const float4*)(De + proc * 4096 + m * 8);
    const float4 d0 = Dp4[0], d1 = Dp4[1];
    const float av = ws[WS_ALPHA + m];
    const float rg = regs[proc * 512 + m];
    for (int i = tid; i < 768; i += 256) {
        sK2[i] = ws[WS_K2 + proc * 768 + i];
        sV2[i] = ws[WS_V2 + proc * 768 + i];
    }
    if (tid < 96) sQq[tid] = ws[WS_QQ + proc * 96 + tid];
    else if (tid >= 96 && tid < 104) sg[tid - 96] = gate[tid - 96];
    __syncthreads();

    // attn2 probs: 16 heads, d=6, 1 query row
    if (tid < 16) {
        const int h0 = tid;
        float lg[8], mx = -1e30f;
        #pragma unroll
        for (int k = 0; k < 8; ++k) {
            float acc = 0.f;
            #pragma unroll
            for (int d = 0; d < 6; ++d)
                acc += sQq[h0 * 6 + d] * sK2[k * 96 + h0 * 6 + d];
            lg[k] = acc * rs; mx = fmaxf(mx, lg[k]);
        }
        float ex[8], sum = 0.f;
        #pragma unroll
        for (int k = 0; k < 8; ++k) { ex[k] = __expf(lg[k] - mx); sum += ex[k]; }
        const float inv = 1.f / sum;
        #pragma unroll
        for (int k = 0; k < 8; ++k) sE2[h0 * 8 + k] = ex[k] * inv;
    }
    __syncthreads();
    if (tid < 96) {           // AV + residual
        const int h0 = tid / 6;
        float o = 0.f;
        #pragma unroll
        for (int k = 0; k < 8; ++k) o += sE2[h0 * 8 + k] * sV2[k * 96 + tid];
        sO[tid] = sQq[tid] + o;
    }
    __syncthreads();
    if (tid < 192) {          // fc2 from LDS, 2-way k-split
        const int j = tid % 96, k2 = tid / 96;
        const float* Os = sO + k2 * 48;
        float acc = 0.f;
        #pragma unroll
        for (int i = 0; i < 48; ++i) acc += Os[i] * sWf2[(k2 * 48 + i) * 96 + j];
        sp[tid] = acc;
    }
    __syncthreads();
    if (tid < 96) sOf[tid] = sO[tid] + fmaxf(sp[tid] + sp[96 + tid], 0.f);
    __syncthreads();

    // Wo slice from LDS: 64 maps, 4-way k-split
    float acc = 0.f;
    #pragma unroll
    for (int i = 0; i < 24; ++i)
        acc += sOf[24 * ks + i] * sWo[(24 * ks + i) * 64 + ml];
    sp[tid] = acc;
    __syncthreads();
    if (ks == 0) {
        const float tr = sp[ml] + sp[ml + 64] + sp[ml + 128] + sp[ml + 192];
        const float de = d0.x * sg[0] + d0.y * sg[1] + d0.z * sg[2] + d0.w * sg[3]
                       + d1.x * sg[4] + d1.y * sg[5] + d1.z * sg[6] + d1.w * sg[7];
        const float mix = av * tr + (1.f - av) * de;
        const int pt = proc & 3;                 // gamma gets +1, beta not
        const float off = (pt == 0 || pt == 2) ? 1.f : 0.f;
        out[proc * 512 + m] = mix * rg + off;
    }
}

extern "C" void kernel_launch(void* const* d_in, const int* in_sizes, int n_in,
                              void* d_out, int out_size, void* d_ws, size_t ws_size,
                              hipStream_t stream)
{
    const float* gate = (const float*)d_in[0];
    const float* x    = (const float*)d_in[1];
    const float* Wa   = (const float*)d_in[2];
    const float* ba   = (const float*)d_in[3];
    const float* Wqr  = (const float*)d_in[4];
    const float* bqr  = (const float*)d_in[5];
    const float* P    = (const float*)d_in[6];
    const float* De   = (const float*)d_in[7];
    const float* regs = (const float*)d_in[8];
    const float* Wq1  = (const float*)d_in[9];
    const float* Wk1  = (const float*)d_in[10];
    const float* Wv1  = (const float*)d_in[11];
    const float* fc1  = (const float*)d_in[12];
    const float* Wq2  = (const float*)d_in[13];
    const float* Wk2  = (const float*)d_in[14];
    const float* Wv2  = (const float*)d_in[15];
    const float* fc2  = (const float*)d_in[16];
    const float* Wo   = (const float*)d_in[17];
    float* ws = (float*)d_ws;

    hipLaunchKernelGGL(kA_qkv_alpha_q, dim3(182), dim3(256), 0, stream,
                       x, Wa, ba, Wqr, bqr, P, Wq1, Wk1, Wv1, ws);
    hipLaunchKernelGGL(kB_attn1_fc1_kv2, dim3(72), dim3(256), 0, stream,
                       fc1, Wk2, Wv2, Wq2, ws);
    hipLaunchKernelGGL(kC_attn2_fc2_out, dim3(64), dim3(256), 0, stream,
                       gate, De, regs, fc2, Wo, ws, (float*)d_out);
}

// Round 10
// 107.915 us; speedup vs baseline: 1.2751x; 1.0136x over previous
//
#include <hip/hip_runtime.h>
#include <hip/hip_bf16.h>
#include <math.h>

// NUM_MAPS=512, ZG=512, HID=96, SEQ=8, H1=3, H2=16, NPROC=8. fp32 in/out.
// R9 confirmed: 3-kernel chain = 109.4us; ~84us harness, ~25us controllable.
// R10: XCD-aware swizzle — proc = blockIdx % 8 everywhere (round-robin
// blockIdx->XCD heuristic), so all same-proc blocks land on one XCD:
// shared weights (fc1 x6, fc2 x8, Wq2 x3, kA line-pair halves) are fetched
// to that XCD's L2 once and L2-hit by siblings. Pure index permutation.

#define WS_ALPHA 0
#define WS_Q     512
#define WS_QKV   608      // 8*2304 -> 19040
#define WS_K2    19040    // 8*768  -> 25184
#define WS_V2    25184    // 8*768  -> 31328
#define WS_QQ    31328    // 8*96   -> 32096

// ---------------------------------------------------------------------------
// KA (182 x 256):
//  blk 0..143   : QKV1. proc = blk%8 (XCD co-location), rem = blk/8 ->
//                 (mat, six). 16 h x 8 s outs; thread (hl16, ks16): 32 W
//                 loads hoisted to regs, K tile skewed in LDS.
//  blk 144..175 : alpha. 16 m/blk, 16-way k-split, W hoisted.
//  blk 176..181 : q. 16 h/blk, 16-way k-split, W hoisted.
// ---------------------------------------------------------------------------
__global__ __launch_bounds__(256) void kA_qkv_alpha_q(
    const float* __restrict__ x, const float* __restrict__ Wa,
    const float* __restrict__ ba, const float* __restrict__ Wqr,
    const float* __restrict__ bqr, const float* __restrict__ P,
    const float* __restrict__ Wq1, const float* __restrict__ Wk1,
    const float* __restrict__ Wv1, float* __restrict__ ws)
{
    __shared__ float sK[8 * 528];   // skewed K tile (c -> c + c/32), or x
    __shared__ float sp[2048];      // partial sums
    const int blk = blockIdx.x, tid = threadIdx.x;

    if (blk < 144) {
        const int proc = blk & 7, rem = blk >> 3;       // proc -> XCD
        const int mat = rem / 6, six = rem % 6;
        const int hl = tid & 15, ks = tid >> 4;        // ks 0..15
        const int h = six * 16 + hl;
        const float* W = (mat == 0 ? Wq1 : (mat == 1 ? Wk1 : Wv1))
                         + proc * 49152 + (ks * 32) * 96 + h;
        float wreg[32];
        #pragma unroll
        for (int m2 = 0; m2 < 32; ++m2) wreg[m2] = W[m2 * 96];  // issued early
        // stage K[s][c] = P[proc,c,s], column skewed c -> c + (c>>5)
        const float4* P4 = (const float4*)(P + proc * 4096);
        for (int i = tid; i < 1024; i += 256) {
            float4 v = P4[i];
            const int c = i >> 1, off = (i & 1) * 4;
            const int cp = c + (c >> 5);
            sK[(off + 0) * 528 + cp] = v.x;
            sK[(off + 1) * 528 + cp] = v.y;
            sK[(off + 2) * 528 + cp] = v.z;
            sK[(off + 3) * 528 + cp] = v.w;
        }
        __syncthreads();
        const float* Kb = sK + ks * 33;                // skewed base
        float acc[8] = {0.f,0.f,0.f,0.f,0.f,0.f,0.f,0.f};
        #pragma unroll
        for (int m2 = 0; m2 < 32; ++m2) {
            const float w = wreg[m2];
            const float* Kc = Kb + m2;
            #pragma unroll
            for (int s = 0; s < 8; ++s) acc[s] += Kc[s * 528] * w;
        }
        float* spb = sp + ks * 128 + hl * 8;
        #pragma unroll
        for (int s = 0; s < 8; ++s) spb[s] = acc[s];
        __syncthreads();
        if (tid < 128) {            // tid = hl2*8 + s
            float a = 0.f;
            #pragma unroll
            for (int u = 0; u < 16; ++u) a += sp[u * 128 + tid];
            const int hl2 = tid >> 3, s = tid & 7;
            ws[WS_QKV + proc * 2304 + mat * 768 + s * 96 + six * 16 + hl2] = a;
        }
    } else if (blk < 176) {
        const int ml = tid & 15, ks = tid >> 4;        // 32 k each
        const int m = (blk - 144) * 16 + ml;
        const float* W = Wa + (ks * 32) * 512 + m;
        float wreg[32];
        #pragma unroll
        for (int k = 0; k < 32; ++k) wreg[k] = W[k * 512];
        for (int k = tid; k < 512; k += 256) sK[k] = x[k];
        __syncthreads();
        const float* xq = sK + ks * 32;
        float acc = 0.f;
        #pragma unroll
        for (int k = 0; k < 32; ++k) acc += xq[k] * wreg[k];
        sp[tid] = acc;
        __syncthreads();
        if (tid < 16) {
            float a = ba[(blk - 144) * 16 + tid];
            #pragma unroll
            for (int u = 0; u < 16; ++u) a += sp[u * 16 + tid];
            ws[WS_ALPHA + (blk - 144) * 16 + tid] = 1.f / (1.f + __expf(-a));
        }
    } else {
        const int hl = tid & 15, ks = tid >> 4;        // 32 k each
        const int h = (blk - 176) * 16 + hl;           // 6*16 = 96
        const float* W = Wqr + (ks * 32) * 96 + h;
        float wreg[32];
        #pragma unroll
        for (int k = 0; k < 32; ++k) wreg[k] = W[k * 96];
        for (int k = tid; k < 512; k += 256) sK[k] = x[k];
        __syncthreads();
        const float* xq = sK + ks * 32;
        float acc = 0.f;
        #pragma unroll
        for (int k = 0; k < 32; ++k) acc += xq[k] * wreg[k];
        sp[tid] = acc;
        __syncthreads();
        if (tid < 16) {
            float a = bqr[(blk - 176) * 16 + tid];
            #pragma unroll
            for (int u = 0; u < 16; ++u) a += sp[u * 16 + tid];
            ws[WS_Q + (blk - 176) * 16 + tid] = fmaxf(a, 0.f);
        }
    }
}

// ---------------------------------------------------------------------------
// KB (72 x 256): blk<48: proc = blk%8 (XCD co-location), slot = blk/8 ->
// (mat, t). Entry burst-stages fc1 (36KB, 6x L2-shared) + Wk2/Wv2 slice
// (12KB) into LDS, then attn1 -> fc1 -> K2/V2 slice.
// blk 48..71: Qq = q @ Wq2; proc = (blk-48)%8, t = (blk-48)/8.
// ---------------------------------------------------------------------------
__global__ __launch_bounds__(256) void kB_attn1_fc1_kv2(
    const float* __restrict__ fc1w, const float* __restrict__ Wk2,
    const float* __restrict__ Wv2, const float* __restrict__ Wq2,
    float* __restrict__ ws)
{
    const int b = blockIdx.x, tid = threadIdx.x;
    const float rs = 0.10206207261596577f;  // 1/sqrt(96)

    if (b < 48) {
        const int proc = b & 7, slot = b >> 3;          // proc -> XCD
        const int mat = slot / 3, t = slot % 3;
        __shared__ float sQk[768], sKk[768], sVv[768], sH[768], sH2[768], sS[192];
        __shared__ float sWf1[9216];     // fc1, row-major [i][j]
        __shared__ float sWkv[96 * 32];  // Wk2/Wv2 column slice [i][jl]

        // ---- entry burst: all weight bytes, coalesced float4, once ----
        {
            const float4* F4 = (const float4*)fc1w + proc * 2304;
            float4* D4 = (float4*)sWf1;
            #pragma unroll
            for (int r = 0; r < 9; ++r) D4[tid + 256 * r] = F4[tid + 256 * r];
            const float4* KV4 = (const float4*)(mat ? Wv2 : Wk2);
            float4* E4 = (float4*)sWkv;
            #pragma unroll
            for (int r = 0; r < 3; ++r) {
                const int idx = tid + 256 * r;          // 768 float4
                const int row = idx >> 3, q4 = idx & 7;
                E4[row * 8 + q4] = KV4[proc * 2304 + row * 24 + t * 8 + q4];
            }
        }
        const float* qkv = ws + WS_QKV + proc * 2304;
        for (int i = tid; i < 768; i += 256) {
            sQk[i] = qkv[i]; sKk[i] = qkv[768 + i]; sVv[i] = qkv[1536 + i];
        }
        __syncthreads();

        if (tid < 192) {       // attn1 logits (h0, si, sk)
            const int h0 = tid / 64, r64 = tid % 64, si = r64 / 8, sk = r64 % 8;
            float acc = 0.f;
            #pragma unroll
            for (int d = 0; d < 32; ++d)
                acc += sQk[si * 96 + h0 * 32 + d] * sKk[sk * 96 + h0 * 32 + d];
            sS[tid] = acc * rs;
        }
        __syncthreads();
        if (tid < 24) {        // softmax row -> probs in place
            float* row = sS + tid * 8;
            float mx = row[0];
            #pragma unroll
            for (int k = 1; k < 8; ++k) mx = fmaxf(mx, row[k]);
            float e[8], sum = 0.f;
            #pragma unroll
            for (int k = 0; k < 8; ++k) { e[k] = __expf(row[k] - mx); sum += e[k]; }
            const float inv = 1.f / sum;
            #pragma unroll
            for (int k = 0; k < 8; ++k) row[k] = e[k] * inv;
        }
        __syncthreads();
        if (tid < 192) {       // AV + residual (h0, si, dq): 4 d's each
            const int h0 = tid / 64, r64 = tid % 64, si = r64 / 8, dq = r64 % 8;
            const float* e = sS + h0 * 64 + si * 8;
            float o0 = 0.f, o1 = 0.f, o2 = 0.f, o3 = 0.f;
            #pragma unroll
            for (int k = 0; k < 8; ++k) {
                const float ek = e[k];
                const float* v = sVv + k * 96 + h0 * 32 + dq * 4;
                o0 += ek*v[0]; o1 += ek*v[1]; o2 += ek*v[2]; o3 += ek*v[3];
            }
            const int base = si * 96 + h0 * 32 + dq * 4;
            sH[base+0] = sQk[base+0] + o0;  sH[base+1] = sQk[base+1] + o1;
            sH[base+2] = sQk[base+2] + o2;  sH[base+3] = sQk[base+3] + o3;
        }
        __syncthreads();
        // fc1 from LDS (full, redundant): 3 outputs/thread
        #pragma unroll
        for (int r = 0; r < 3; ++r) {
            const int idx = tid + 256 * r, s = idx / 96, j = idx % 96;
            const float* Hs = sH + s * 96;
            float acc = 0.f;
            #pragma unroll
            for (int i = 0; i < 96; ++i) acc += Hs[i] * sWf1[i * 96 + j];
            sH2[idx] = sH[idx] + fmaxf(acc, 0.f);
        }
        __syncthreads();
        // K2/V2 slice from LDS: (s, jl)
        const int s = tid >> 5, jl = tid & 31, j = t * 32 + jl;
        const float* Hs = sH2 + s * 96;
        float acc = 0.f;
        #pragma unroll
        for (int i = 0; i < 96; ++i) acc += Hs[i] * sWkv[i * 32 + jl];
        ws[(mat ? WS_V2 : WS_K2) + proc * 768 + s * 96 + j] = acc;
    } else {
        const int b2 = b - 48, proc = b2 & 7, t = b2 >> 3;   // proc -> XCD
        __shared__ float sq[96], sp[256];
        if (tid < 96) sq[tid] = ws[WS_Q + tid];
        __syncthreads();
        const int jl = tid & 31, ks = tid >> 5;
        const int j = 32 * t + jl;
        const float* W = Wq2 + proc * 9216 + j;
        float acc = 0.f;
        #pragma unroll
        for (int i = 0; i < 12; ++i)
            acc += sq[12 * ks + i] * W[(12 * ks + i) * 96];
        sp[tid] = acc;
        __syncthreads();
        if (ks == 0) {
            float a = 0.f;
            #pragma unroll
            for (int u = 0; u < 8; ++u) a += sp[jl + 32 * u];
            ws[WS_QQ + proc * 96 + j] = a;
        }
    }
}

// ---------------------------------------------------------------------------
// KC (64 x 256): proc = blk%8 (XCD co-location), e = blk/8. Entry burst-
// stages fc2 (36KB, 8x L2-shared) + Wo slice (24KB) into LDS + K2/V2/Qq
// from ws + De/alpha/regs into regs. Then attn2, fc2, Wo slice + epilogue.
// ---------------------------------------------------------------------------
__global__ __launch_bounds__(256) void kC_attn2_fc2_out(
    const float* __restrict__ gate, const float* __restrict__ De,
    const float* __restrict__ regs, const float* __restrict__ fc2w,
    const float* __restrict__ Wo, const float* __restrict__ ws,
    float* __restrict__ out)
{
    const int b = blockIdx.x, proc = b & 7, e = b >> 3, tid = threadIdx.x;
    __shared__ float sK2[768], sV2[768];
    __shared__ float sQq[96], sO[96], sOf[96], sE2[128], sg[8], sp[256];
    __shared__ float sWf2[9216];     // fc2 [i][j]
    __shared__ float sWo[96 * 64];   // Wo slice [h][ml]
    const float rs = 0.10206207261596577f;

    // ---- entry burst ----
    {
        const float4* F4 = (const float4*)fc2w + proc * 2304;
        float4* D4 = (float4*)sWf2;
        #pragma unroll
        for (int r = 0; r < 9; ++r) D4[tid + 256 * r] = F4[tid + 256 * r];
        const float4* W4 = (const float4*)Wo;
        float4* E4 = (float4*)sWo;
        #pragma unroll
        for (int r = 0; r < 6; ++r) {
            const int idx = tid + 256 * r;              // 1536 float4
            const int row = idx >> 4, q4 = idx & 15;
            E4[row * 16 + q4] = W4[proc * 12288 + row * 128 + e * 16 + q4];
        }
    }
    const int ml = tid & 63, ks = tid >> 6;
    const int m = 64 * e + ml;
    // epilogue operands prefetched into regs (redundant across ks, cheap)
    const float4* Dp4 = (const float4*)(De + proc * 4096 + m * 8);
    const float4 d0 = Dp4[0], d1 = Dp4[1];
    const float av = ws[WS_ALPHA + m];
    const float rg = regs[proc * 512 + m];
    for (int i = tid; i < 768; i += 256) {
        sK2[i] = ws[WS_K2 + proc * 768 + i];
        sV2[i] = ws[WS_V2 + proc * 768 + i];
    }
    if (tid < 96) sQq[tid] = ws[WS_QQ + proc * 96 + tid];
    else if (tid >= 96 && tid < 104) sg[tid - 96] = gate[tid - 96];
    __syncthreads();

    // attn2 probs: 16 heads, d=6, 1 query row
    if (tid < 16) {
        const int h0 = tid;
        float lg[8], mx = -1e30f;
        #pragma unroll
        for (int k = 0; k < 8; ++k) {
            float acc = 0.f;
            #pragma unroll
            for (int d = 0; d < 6; ++d)
                acc += sQq[h0 * 6 + d] * sK2[k * 96 + h0 * 6 + d];
            lg[k] = acc * rs; mx = fmaxf(mx, lg[k]);
        }
        float ex[8], sum = 0.f;
        #pragma unroll
        for (int k = 0; k < 8; ++k) { ex[k] = __expf(lg[k] - mx); sum += ex[k]; }
        const float inv = 1.f / sum;
        #pragma unroll
        for (int k = 0; k < 8; ++k) sE2[h0 * 8 + k] = ex[k] * inv;
    }
    __syncthreads();
    if (tid < 96) {           // AV + residual
        const int h0 = tid / 6;
        float o = 0.f;
        #pragma unroll
        for (int k = 0; k < 8; ++k) o += sE2[h0 * 8 + k] * sV2[k * 96 + tid];
        sO[tid] = sQq[tid] + o;
    }
    __syncthreads();
    if (tid < 192) {          // fc2 from LDS, 2-way k-split
        const int j = tid % 96, k2 = tid / 96;
        const float* Os = sO + k2 * 48;
        float acc = 0.f;
        #pragma unroll
        for (int i = 0; i < 48; ++i) acc += Os[i] * sWf2[(k2 * 48 + i) * 96 + j];
        sp[tid] = acc;
    }
    __syncthreads();
    if (tid < 96) sOf[tid] = sO[tid] + fmaxf(sp[tid] + sp[96 + tid], 0.f);
    __syncthreads();

    // Wo slice from LDS: 64 maps, 4-way k-split
    float acc = 0.f;
    #pragma unroll
    for (int i = 0; i < 24; ++i)
        acc += sOf[24 * ks + i] * sWo[(24 * ks + i) * 64 + ml];
    sp[tid] = acc;
    __syncthreads();
    if (ks == 0) {
        const float tr = sp[ml] + sp[ml + 64] + sp[ml + 128] + sp[ml + 192];
        const float de = d0.x * sg[0] + d0.y * sg[1] + d0.z * sg[2] + d0.w * sg[3]
                       + d1.x * sg[4] + d1.y * sg[5] + d1.z * sg[6] + d1.w * sg[7];
        const float mix = av * tr + (1.f - av) * de;
        const int pt = proc & 3;                 // gamma gets +1, beta not
        const float off = (pt == 0 || pt == 2) ? 1.f : 0.f;
        out[proc * 512 + m] = mix * rg + off;
    }
}

extern "C" void kernel_launch(void* const* d_in, const int* in_sizes, int n_in,
                              void* d_out, int out_size, void* d_ws, size_t ws_size,
                              hipStream_t stream)
{
    const float* gate = (const float*)d_in[0];
    const float* x    = (const float*)d_in[1];
    const float* Wa   = (const float*)d_in[2];
    const float* ba   = (const float*)d_in[3];
    const float* Wqr  = (const float*)d_in[4];
    const float* bqr  = (const float*)d_in[5];
    const float* P    = (const float*)d_in[6];
    const float* De   = (const float*)d_in[7];
    const float* regs = (const float*)d_in[8];
    const float* Wq1  = (const float*)d_in[9];
    const float* Wk1  = (const float*)d_in[10];
    const float* Wv1  = (const float*)d_in[11];
    const float* fc1  = (const float*)d_in[12];
    const float* Wq2  = (const float*)d_in[13];
    const float* Wk2  = (const float*)d_in[14];
    const float* Wv2  = (const float*)d_in[15];
    const float* fc2  = (const float*)d_in[16];
    const float* Wo   = (const float*)d_in[17];
    float* ws = (float*)d_ws;

    hipLaunchKernelGGL(kA_qkv_alpha_q, dim3(182), dim3(256), 0, stream,
                       x, Wa, ba, Wqr, bqr, P, Wq1, Wk1, Wv1, ws);
    hipLaunchKernelGGL(kB_attn1_fc1_kv2, dim3(72), dim3(256), 0, stream,
                       fc1, Wk2, Wv2, Wq2, ws);
    hipLaunchKernelGGL(kC_attn2_fc2_out, dim3(64), dim3(256), 0, stream,
                       gate, De, regs, fc2, Wo, ws, (float*)d_out);
}